// Round 3
// baseline (298.635 us; speedup 1.0000x reference)
//
#include <hip/hip_runtime.h>

#define D_MODEL 1024
#define TSEQ    4096
#define BATCH   4
#define MROWS   (BATCH * TSEQ)   // 16384
#define KDIM    1024
#define NDIM    1024
#define EPSV    1e-6f

typedef __attribute__((ext_vector_type(8))) short short8;
typedef __attribute__((ext_vector_type(4))) float floatx4;

__device__ inline unsigned short f2bf(float f) {
  unsigned u = __float_as_uint(f);
  unsigned r = (u + 0x7FFFu + ((u >> 16) & 1u)) >> 16;  // RNE
  return (unsigned short)r;
}
__device__ inline float phi_f(float x) { return x > 0.f ? x + 1.f : __expf(x); }

// async global->LDS, 16B per lane (linear dest = wave base + lane*16)
#define GLD16(gp, lp) __builtin_amdgcn_global_load_lds( \
    (const __attribute__((address_space(1))) void*)(gp), \
    (__attribute__((address_space(3))) void*)(lp), 16, 0, 0)

#define VMCNT8() asm volatile("s_waitcnt vmcnt(8)" ::: "memory")
#define VMCNT0() asm volatile("s_waitcnt vmcnt(0)" ::: "memory")

// ---------------- fused prep: fp32->bf16 (x + 4 weights) + zero ksum/kvsum ----
#define NX4 4194304   // x float4 count
#define NW4 262144    // one weight float4 count
#define NZ4 2048      // ksum+kvsum float4 count

__global__ __launch_bounds__(256) void prep_kernel(
    const float* __restrict__ x,  const float* __restrict__ wq,
    const float* __restrict__ wk, const float* __restrict__ wv,
    const float* __restrict__ wg,
    unsigned short* __restrict__ xb,  unsigned short* __restrict__ wqb,
    unsigned short* __restrict__ wkb, unsigned short* __restrict__ wvb,
    unsigned short* __restrict__ wgb, float* __restrict__ zbase)
{
  long i = (long)blockIdx.x * 256 + threadIdx.x;
  const float* src; unsigned short* dst; long j = i;
  if (j < NX4) { src = x; dst = xb; }
  else {
    j -= NX4;
    if (j < NW4) { src = wq; dst = wqb; }
    else { j -= NW4;
      if (j < NW4) { src = wk; dst = wkb; }
      else { j -= NW4;
        if (j < NW4) { src = wv; dst = wvb; }
        else { j -= NW4;
          if (j < NW4) { src = wg; dst = wgb; }
          else { j -= NW4;
            if (j < NZ4) { float4 zz = {0.f,0.f,0.f,0.f}; ((float4*)zbase)[j] = zz; }
            return;
          }
        }
      }
    }
  }
  float4 f = ((const float4*)src)[j];
  ushort4 o;
  o.x = f2bf(f.x); o.y = f2bf(f.y); o.z = f2bf(f.z); o.w = f2bf(f.w);
  ((ushort4*)dst)[j] = o;
}

// ---------------- phase-split GEMM geometry ---------------------------------
// 256(M) x 128(N) tile, BK=64, 512 threads (8 waves). 16 K-steps, 4 phases
// each. LDS rows are 128 B -> T2 XOR swizzle slot^=row&7 on 16B slots
// (verified round 2: bank conflicts 8.4M -> 0). Counted-vmcnt pipeline (T4):
// stage(t+2) issued at the t/t+1 boundary, wait vmcnt(8) = drain only t+1's
// loads; vmcnt(0) only at the tail. Stage issue is AFTER the phase-3 post-MFMA
// barrier: every wave's ds_reads of that buffer completed (lgkmcnt(0) precedes
// its MFMA, which precedes the barrier), so the overwrite is race-free.
#define BM 256
#define BN 128
#define BK 64
#define NSTEP (KDIM / BK)   // 16

// ---------------- phase 1: k/v GEMM with in-register fused reduction --------
__global__ __launch_bounds__(512, 1) void gemm_kv_kernel(
    const unsigned short* __restrict__ A,
    const unsigned short* __restrict__ Wk, const unsigned short* __restrict__ Wv,
    float* __restrict__ ksum, float* __restrict__ kvsum)
{
  __shared__ __align__(16) unsigned short As0[BM * BK], As1[BM * BK];   // 64 KB
  __shared__ __align__(16) unsigned short Bk0[BN * BK], Bk1[BN * BK];   // 32 KB
  __shared__ __align__(16) unsigned short Bv0[BN * BK], Bv1[BN * BK];   // 32 KB

  // T1 bijective XCD swizzle: 512 blocks = 8 xcd * 64
  const int bid = blockIdx.x;
  const int sw  = (bid & 7) * 64 + (bid >> 3);
  const int bn  = sw & 7;    // 0..7
  const int bm  = sw >> 3;   // 0..63

  const int tid  = threadIdx.x;
  const int lane = tid & 63;
  const int w    = tid >> 6;           // 0..7
  const int wr   = (w >> 2) * 128;     // 2 row groups
  const int wc   = (w & 3) * 32;       // 4 col groups
  const int la   = lane & 15;
  const int l4   = lane >> 4;

  floatx4 ak[8][2], av[8][2];
#pragma unroll
  for (int i = 0; i < 8; i++)
#pragma unroll
    for (int j = 0; j < 2; j++) {
      floatx4 zz = {0.f,0.f,0.f,0.f}; ak[i][j] = zz; av[i][j] = zz;
    }

  const unsigned short* Ablk = A  + (size_t)bm * BM * KDIM;
  const unsigned short* Bkb  = Wk + (size_t)bn * BN * KDIM;
  const unsigned short* Bvb  = Wv + (size_t)bn * BN * KDIM;

  // hoisted per-thread staging offsets (element units), swizzled source col
  int aoff[4], boff[2];
#pragma unroll
  for (int i = 0; i < 4; i++) {
    int s = tid + i * 512; int r = s >> 3;
    aoff[i] = r * KDIM + (((s & 7) ^ (r & 7)) << 3);
  }
#pragma unroll
  for (int i = 0; i < 2; i++) {
    int s = tid + i * 512; int r = s >> 3;
    boff[i] = r * KDIM + (((s & 7) ^ (r & 7)) << 3);
  }

  auto stage8 = [&](unsigned short* Aw, unsigned short* Bkw, unsigned short* Bvw,
                    int kt) {
#pragma unroll
    for (int i = 0; i < 4; ++i)
      GLD16(Ablk + aoff[i] + kt, Aw + (size_t)(tid + i * 512) * 8);
#pragma unroll
    for (int i = 0; i < 2; ++i) {
      GLD16(Bkb + boff[i] + kt, Bkw + (size_t)(tid + i * 512) * 8);
      GLD16(Bvb + boff[i] + kt, Bvw + (size_t)(tid + i * 512) * 8);
    }
  };

  // LDS read swizzle: slot = (kk*4+l4) ^ (la&7)  (row&7 == la&7 here)
  const int sl0 = (0 * 4 + l4) ^ (la & 7);
  const int sl1 = (1 * 4 + l4) ^ (la & 7);

  auto kphases = [&](const unsigned short* Ar, const unsigned short* Bkr,
                     const unsigned short* Bvr) {
    short8 bkf[2][2], bvf[2][2];
#pragma unroll
    for (int p = 0; p < 4; ++p) {
      short8 af[2][2];
#pragma unroll
      for (int rp = 0; rp < 2; ++rp) {
        int row = wr + (2 * p + rp) * 16 + la;
        af[rp][0] = *(const short8*)(Ar + row * BK + sl0 * 8);
        af[rp][1] = *(const short8*)(Ar + row * BK + sl1 * 8);
      }
      if (p == 0) {
#pragma unroll
        for (int j = 0; j < 2; ++j) {
          int row = wc + j * 16 + la;
          bkf[j][0] = *(const short8*)(Bkr + row * BK + sl0 * 8);
          bkf[j][1] = *(const short8*)(Bkr + row * BK + sl1 * 8);
          bvf[j][0] = *(const short8*)(Bvr + row * BK + sl0 * 8);
          bvf[j][1] = *(const short8*)(Bvr + row * BK + sl1 * 8);
        }
      }
      __builtin_amdgcn_s_barrier();
      __builtin_amdgcn_s_setprio(1);
#pragma unroll
      for (int rp = 0; rp < 2; ++rp)
#pragma unroll
        for (int j = 0; j < 2; ++j)
#pragma unroll
          for (int kk = 0; kk < 2; ++kk) {
            ak[2*p+rp][j] = __builtin_amdgcn_mfma_f32_16x16x32_bf16(
                af[rp][kk], bkf[j][kk], ak[2*p+rp][j], 0, 0, 0);
            av[2*p+rp][j] = __builtin_amdgcn_mfma_f32_16x16x32_bf16(
                af[rp][kk], bvf[j][kk], av[2*p+rp][j], 0, 0, 0);
          }
      __builtin_amdgcn_s_setprio(0);
      __builtin_amdgcn_s_barrier();
    }
  };

  // prologue: two K-steps in flight, counted wait on the first
  stage8(As0, Bk0, Bv0, 0);
  stage8(As1, Bk1, Bv1, BK);
  VMCNT8();
  __builtin_amdgcn_s_barrier();

  for (int st2 = 0; st2 < NSTEP; st2 += 2) {
    kphases(As0, Bk0, Bv0);                       // step st2 (buf0)
    if (st2 + 2 < NSTEP) { stage8(As0, Bk0, Bv0, (st2 + 2) * BK); VMCNT8(); }
    else                 { VMCNT0(); }            // tail: wait last step's loads
    __builtin_amdgcn_s_barrier();
    kphases(As1, Bk1, Bv1);                       // step st2+1 (buf1)
    if (st2 + 3 < NSTEP) {
      stage8(As1, Bk1, Bv1, (st2 + 3) * BK); VMCNT8();
      __builtin_amdgcn_s_barrier();
    } else if (st2 + 2 < NSTEP) {
      VMCNT0();
      __builtin_amdgcn_s_barrier();
    }
  }

  // ---- fused column reduction ----
  const int b = bm >> 4;               // 16 bm-blocks per batch (256 rows each)
  float kp[2] = {0.f, 0.f};
  float vp[2] = {0.f, 0.f};
#pragma unroll
  for (int j = 0; j < 2; j++)
#pragma unroll
    for (int mi = 0; mi < 8; mi++)
#pragma unroll
      for (int r = 0; r < 4; r++) {
        float kk = phi_f(ak[mi][j][r]);
        kp[j] += kk;
        vp[j] += kk * av[mi][j][r];
      }
#pragma unroll
  for (int j = 0; j < 2; j++) {
    kp[j] += __shfl_xor(kp[j], 16, 64); kp[j] += __shfl_xor(kp[j], 32, 64);
    vp[j] += __shfl_xor(vp[j], 16, 64); vp[j] += __shfl_xor(vp[j], 32, 64);
  }
  if (lane < 16) {
#pragma unroll
    for (int j = 0; j < 2; j++) {
      int col = bn * BN + wc + j * 16 + lane;
      atomicAdd(ksum  + (size_t)b * D_MODEL + col, kp[j]);
      atomicAdd(kvsum + (size_t)b * D_MODEL + col, vp[j]);
    }
  }
}

// ---------------- phase 2: q/g GEMM with fused finalize ---------------------
// Waves 0-3 compute q on 256x128 (128x64 each), waves 4-7 compute g. A wave's
// 64 cols = exactly one head -> s,z reduce fully in-wave.
__global__ __launch_bounds__(512, 1) void gemm_qg_kernel(
    const unsigned short* __restrict__ A,
    const unsigned short* __restrict__ Wq, const unsigned short* __restrict__ Wg,
    const float* __restrict__ x, const float* __restrict__ bg,
    const float* __restrict__ ksum, const float* __restrict__ kvsum,
    float* __restrict__ out)
{
  __shared__ __align__(16) unsigned short As0[BM * BK], As1[BM * BK];
  __shared__ __align__(16) unsigned short Bq0[BN * BK], Bq1[BN * BK];
  __shared__ __align__(16) unsigned short Bg0[BN * BK], Bg1[BN * BK];
  __shared__ float o_lds[2 * BM];      // [head_local][row_local]

  const int bid = blockIdx.x;
  const int sw  = (bid & 7) * 64 + (bid >> 3);
  const int bn  = sw & 7;
  const int bm  = sw >> 3;

  const int tid  = threadIdx.x;
  const int lane = tid & 63;
  const int w    = tid >> 6;           // 0..7
  const int is_g = w >> 2;
  const int wl   = w & 3;
  const int wr   = (wl >> 1) * 128;
  const int wc   = (wl & 1) * 64;
  const int la   = lane & 15;
  const int l4   = lane >> 4;

  floatx4 acc[8][4];
#pragma unroll
  for (int i = 0; i < 8; i++)
#pragma unroll
    for (int j = 0; j < 4; j++) { floatx4 zz = {0.f,0.f,0.f,0.f}; acc[i][j] = zz; }

  const unsigned short* Ablk = A  + (size_t)bm * BM * KDIM;
  const unsigned short* Bqb  = Wq + (size_t)bn * BN * KDIM;
  const unsigned short* Bgb  = Wg + (size_t)bn * BN * KDIM;

  int aoff[4], boff[2];
#pragma unroll
  for (int i = 0; i < 4; i++) {
    int s = tid + i * 512; int r = s >> 3;
    aoff[i] = r * KDIM + (((s & 7) ^ (r & 7)) << 3);
  }
#pragma unroll
  for (int i = 0; i < 2; i++) {
    int s = tid + i * 512; int r = s >> 3;
    boff[i] = r * KDIM + (((s & 7) ^ (r & 7)) << 3);
  }

  auto stage8 = [&](unsigned short* Aw, unsigned short* Bqw, unsigned short* Bgw,
                    int kt) {
#pragma unroll
    for (int i = 0; i < 4; ++i)
      GLD16(Ablk + aoff[i] + kt, Aw + (size_t)(tid + i * 512) * 8);
#pragma unroll
    for (int i = 0; i < 2; ++i) {
      GLD16(Bqb + boff[i] + kt, Bqw + (size_t)(tid + i * 512) * 8);
      GLD16(Bgb + boff[i] + kt, Bgw + (size_t)(tid + i * 512) * 8);
    }
  };

  const int sl0 = (0 * 4 + l4) ^ (la & 7);
  const int sl1 = (1 * 4 + l4) ^ (la & 7);

  auto kphases = [&](const unsigned short* Ar, const unsigned short* Br) {
    short8 bf[4][2];
#pragma unroll
    for (int p = 0; p < 4; ++p) {
      short8 af[2][2];
#pragma unroll
      for (int rp = 0; rp < 2; ++rp) {
        int row = wr + (2 * p + rp) * 16 + la;
        af[rp][0] = *(const short8*)(Ar + row * BK + sl0 * 8);
        af[rp][1] = *(const short8*)(Ar + row * BK + sl1 * 8);
      }
      if (p == 0) {
#pragma unroll
        for (int j = 0; j < 4; ++j) {
          int row = wc + j * 16 + la;
          bf[j][0] = *(const short8*)(Br + row * BK + sl0 * 8);
          bf[j][1] = *(const short8*)(Br + row * BK + sl1 * 8);
        }
      }
      __builtin_amdgcn_s_barrier();
      __builtin_amdgcn_s_setprio(1);
#pragma unroll
      for (int rp = 0; rp < 2; ++rp)
#pragma unroll
        for (int j = 0; j < 4; ++j)
#pragma unroll
          for (int kk = 0; kk < 2; ++kk)
            acc[2*p+rp][j] = __builtin_amdgcn_mfma_f32_16x16x32_bf16(
                af[rp][kk], bf[j][kk], acc[2*p+rp][j], 0, 0, 0);
      __builtin_amdgcn_s_setprio(0);
      __builtin_amdgcn_s_barrier();
    }
  };

  stage8(As0, Bq0, Bg0, 0);
  stage8(As1, Bq1, Bg1, BK);
  VMCNT8();
  __builtin_amdgcn_s_barrier();

  for (int st2 = 0; st2 < NSTEP; st2 += 2) {
    kphases(As0, is_g ? Bg0 : Bq0);               // step st2 (buf0)
    if (st2 + 2 < NSTEP) { stage8(As0, Bq0, Bg0, (st2 + 2) * BK); VMCNT8(); }
    else                 { VMCNT0(); }
    __builtin_amdgcn_s_barrier();
    kphases(As1, is_g ? Bg1 : Bq1);               // step st2+1 (buf1)
    if (st2 + 3 < NSTEP) {
      stage8(As1, Bq1, Bg1, (st2 + 3) * BK); VMCNT8();
      __builtin_amdgcn_s_barrier();
    } else if (st2 + 2 < NSTEP) {
      VMCNT0();
      __builtin_amdgcn_s_barrier();
    }
  }

  // ---- fused finalize ----
  const int b  = bm >> 4;
  const int ro = l4 * 4;
  const int co = la;
  const int hl = wc >> 6;              // head_local (0/1): wave spans one head

  if (!is_g) {
    float kvv[4], ksv[4];
#pragma unroll
    for (int j = 0; j < 4; j++) {
      int col = bn * BN + wc + j * 16 + co;
      kvv[j] = kvsum[(size_t)b * D_MODEL + col];
      ksv[j] = ksum [(size_t)b * D_MODEL + col];
    }
#pragma unroll
    for (int mi = 0; mi < 8; mi++)
#pragma unroll
      for (int r = 0; r < 4; r++) {
        float s = 0.f, z = 0.f;
#pragma unroll
        for (int j = 0; j < 4; j++) {
          float qq = phi_f(acc[mi][j][r]);
          s += qq * kvv[j]; z += qq * ksv[j];
        }
#pragma unroll
        for (int m = 1; m < 16; m <<= 1) {
          s += __shfl_xor(s, m, 64);
          z += __shfl_xor(z, m, 64);
        }
        if (co == 0) o_lds[hl * BM + wr + mi * 16 + ro + r] = s / (z + EPSV);
      }
  }
  __syncthreads();
  if (is_g) {
    float bgv[4];
#pragma unroll
    for (int j = 0; j < 4; j++) bgv[j] = bg[bn * BN + wc + j * 16 + co];
#pragma unroll
    for (int mi = 0; mi < 8; mi++)
#pragma unroll
      for (int r = 0; r < 4; r++) {
        int rowl = wr + mi * 16 + ro + r;
        int grow = bm * BM + rowl;
        float ov = o_lds[hl * BM + rowl];
#pragma unroll
        for (int j = 0; j < 4; j++) {
          int gcol = bn * BN + wc + j * 16 + co;
          float gt = 1.f / (1.f + __expf(-(acc[mi][j][r] + bgv[j])));
          float xv = x[(size_t)grow * D_MODEL + gcol];
          out[(size_t)grow * D_MODEL + gcol] = gt * ov + (1.f - gt) * xv;
        }
      }
  }
}

extern "C" void kernel_launch(void* const* d_in, const int* in_sizes, int n_in,
                              void* d_out, int out_size, void* d_ws, size_t ws_size,
                              hipStream_t stream) {
  (void)in_sizes; (void)n_in; (void)out_size; (void)ws_size;
  const float* x  = (const float*)d_in[0];
  const float* Wq = (const float*)d_in[1];
  const float* Wk = (const float*)d_in[2];
  const float* Wv = (const float*)d_in[3];
  /* d_in[4] = Wo — unused by the reference */
  const float* Wg = (const float*)d_in[5];
  const float* bg = (const float*)d_in[6];
  float* out = (float*)d_out;

  char* ws = (char*)d_ws;
  const size_t xel = (size_t)MROWS * D_MODEL;
  const size_t wel = (size_t)NDIM * KDIM;
  unsigned short* xbf = (unsigned short*)ws; ws += xel * 2;
  unsigned short* wqb = (unsigned short*)ws; ws += wel * 2;
  unsigned short* wkb = (unsigned short*)ws; ws += wel * 2;
  unsigned short* wvb = (unsigned short*)ws; ws += wel * 2;
  unsigned short* wgb = (unsigned short*)ws; ws += wel * 2;
  float* ksum  = (float*)ws; ws += (size_t)BATCH * D_MODEL * 4;  // contiguous
  float* kvsum = (float*)ws; ws += (size_t)BATCH * D_MODEL * 4;

  // 1) fused converts + zero
  const long total4 = (long)NX4 + 4L * NW4 + NZ4;
  prep_kernel<<<(int)((total4 + 255) / 256), 256, 0, stream>>>(
      x, Wq, Wk, Wv, Wg, xbf, wqb, wkb, wvb, wgb, ksum);

  // 2) phase 1: k/v with fused reduction (512 blocks = 8 bn x 64 bm)
  gemm_kv_kernel<<<512, 512, 0, stream>>>(xbf, wkb, wvb, ksum, kvsum);

  // 3) phase 2: q/g with fused finalize
  gemm_qg_kernel<<<512, 512, 0, stream>>>(xbf, wqb, wgb, x, bg, ksum, kvsum, out);
}

// Round 4
// 286.169 us; speedup vs baseline: 1.0436x; 1.0436x over previous
//
#include <hip/hip_runtime.h>

#define D_MODEL 1024
#define TSEQ    4096
#define BATCH   4
#define MROWS   (BATCH * TSEQ)   // 16384
#define KDIM    1024
#define NDIM    1024
#define EPSV    1e-6f

typedef __attribute__((ext_vector_type(8))) short short8;
typedef __attribute__((ext_vector_type(4))) float floatx4;

__device__ inline unsigned short f2bf(float f) {
  unsigned u = __float_as_uint(f);
  unsigned r = (u + 0x7FFFu + ((u >> 16) & 1u)) >> 16;  // RNE
  return (unsigned short)r;
}
__device__ inline float phi_f(float x) { return x > 0.f ? x + 1.f : __expf(x); }

// async global->LDS, 16B per lane (linear dest = wave base + lane*16)
#define GLD16(gp, lp) __builtin_amdgcn_global_load_lds( \
    (const __attribute__((address_space(1))) void*)(gp), \
    (__attribute__((address_space(3))) void*)(lp), 16, 0, 0)

#define VMCNT7() asm volatile("s_waitcnt vmcnt(7)" ::: "memory")
#define VMCNT0() asm volatile("s_waitcnt vmcnt(0)" ::: "memory")

// ---------------- fused prep: fp32->bf16 (x + 4 weights) + zero ksum/kvsum ----
#define NX4 4194304   // x float4 count
#define NW4 262144    // one weight float4 count
#define NZ4 2048      // ksum+kvsum float4 count

__global__ __launch_bounds__(256) void prep_kernel(
    const float* __restrict__ x,  const float* __restrict__ wq,
    const float* __restrict__ wk, const float* __restrict__ wv,
    const float* __restrict__ wg,
    unsigned short* __restrict__ xb,  unsigned short* __restrict__ wqb,
    unsigned short* __restrict__ wkb, unsigned short* __restrict__ wvb,
    unsigned short* __restrict__ wgb, float* __restrict__ zbase)
{
  long i = (long)blockIdx.x * 256 + threadIdx.x;
  const float* src; unsigned short* dst; long j = i;
  if (j < NX4) { src = x; dst = xb; }
  else {
    j -= NX4;
    if (j < NW4) { src = wq; dst = wqb; }
    else { j -= NW4;
      if (j < NW4) { src = wk; dst = wkb; }
      else { j -= NW4;
        if (j < NW4) { src = wv; dst = wvb; }
        else { j -= NW4;
          if (j < NW4) { src = wg; dst = wgb; }
          else { j -= NW4;
            if (j < NZ4) { float4 zz = {0.f,0.f,0.f,0.f}; ((float4*)zbase)[j] = zz; }
            return;
          }
        }
      }
    }
  }
  float4 f = ((const float4*)src)[j];
  ushort4 o;
  o.x = f2bf(f.x); o.y = f2bf(f.y); o.z = f2bf(f.z); o.w = f2bf(f.w);
  ((ushort4*)dst)[j] = o;
}

// ---------------- phase-split GEMM geometry ---------------------------------
// 256(M) x 128(N) tile, BK=64, 512 threads (8 waves). 16 K-steps, 4 phases.
// Fine-interleaved counted pipeline (m201 pattern):
//  - phase p consumes A-quarter p (rows {32p..+32} U {128+32p..+32}) and ALL B
//    rows at phase 0 -> A-quarter q is overwritable from phase q+1, B from
//    phase 1. So step t+2's loads are issued INSIDE step t's phases:
//    p0: A-q3 of step t+1 (straggler, other buffer); p1: A-q0 + B1-c0;
//    p2: A-q1 + B1-c1 + B2-c0; p3: A-q2 + B2-c1.  (8 loads/step/thread)
//  - one counted wait per step: vmcnt(7) at phase-3 tail drains step t+1's 8
//    loads (issued >= 1 step earlier), leaves step t+2's 7 in flight.
//    vmcnt(0) only before the final step. Never drain-0 in steady state.
//  - LDS XOR swizzle slot^=row&7 (bank conflicts = 0, verified round 2),
//    applied via inverse-swizzled GLOBAL source + swizzled ds_read.
#define BM 256
#define BN 128
#define BK 64
#define NSTEP (KDIM / BK)   // 16

// ---------------- phase 1: k/v GEMM with in-register fused reduction --------
__global__ __launch_bounds__(512, 1) void gemm_kv_kernel(
    const unsigned short* __restrict__ A,
    const unsigned short* __restrict__ Wk, const unsigned short* __restrict__ Wv,
    float* __restrict__ ksum, float* __restrict__ kvsum)
{
  __shared__ __align__(16) unsigned short As0[BM * BK], As1[BM * BK];   // 64 KB
  __shared__ __align__(16) unsigned short Bk0[BN * BK], Bk1[BN * BK];   // 32 KB
  __shared__ __align__(16) unsigned short Bv0[BN * BK], Bv1[BN * BK];   // 32 KB

  // T1 bijective XCD swizzle: 512 blocks = 8 xcd * 64
  const int bid = blockIdx.x;
  const int sw  = (bid & 7) * 64 + (bid >> 3);
  const int bn  = sw & 7;    // 0..7
  const int bm  = sw >> 3;   // 0..63

  const int tid  = threadIdx.x;
  const int lane = tid & 63;
  const int w    = tid >> 6;           // 0..7
  const int wr   = (w >> 2) * 128;     // 2 row groups
  const int wc   = (w & 3) * 32;       // 4 col groups
  const int la   = lane & 15;
  const int l4   = lane >> 4;

  floatx4 ak[8][2], av[8][2];
#pragma unroll
  for (int i = 0; i < 8; i++)
#pragma unroll
    for (int j = 0; j < 2; j++) {
      floatx4 zz = {0.f,0.f,0.f,0.f}; ak[i][j] = zz; av[i][j] = zz;
    }

  const unsigned short* Ablk = A  + (size_t)bm * BM * KDIM;
  const unsigned short* Bkb  = Wk + (size_t)bn * BN * KDIM;
  const unsigned short* Bvb  = Wv + (size_t)bn * BN * KDIM;

  // A staging: quarter p = rows [32p,32p+32) U [128+32p,128+32p+32).
  // thread covers local row lr = tid>>3, slot slt = tid&7 (16B units).
  const int lr  = tid >> 3;                       // 0..63
  const int slt = tid & 7;
  const int arb = (lr & 31) + ((lr >> 5) << 7);   // quarter-relative row base
  const int aG  = arb * KDIM + ((slt ^ (lr & 7)) << 3);  // swizzled global src
  const int aL  = arb * BK + slt * 8;             // linear LDS dest (elements)
  // B staging: chunk i = rows [64i, 64i+64)
  int boff[2], bL[2];
#pragma unroll
  for (int i = 0; i < 2; i++) {
    int s = tid + i * 512; int r = s >> 3;
    boff[i] = r * KDIM + (((s & 7) ^ (r & 7)) << 3);
    bL[i]   = s * 8;
  }

  auto SA = [&](unsigned short* dst, int s, int p) {
    GLD16(Ablk + aG + (32 * p) * KDIM + s * BK, dst + aL + p * (32 * BK));
  };
  auto SB = [&](const unsigned short* g, unsigned short* dst, int s, int i) {
    GLD16(g + boff[i] + s * BK, dst + bL[i]);
  };

  // LDS read swizzle: slot = (kk*4+l4) ^ (la&7)  (row&7 == la&7 everywhere)
  const int sl0 = (0 * 4 + l4) ^ (la & 7);
  const int sl1 = (1 * 4 + l4) ^ (la & 7);

  // one K-step t: read bufR(Ar,Bkr,Bvr); straggler A-q3 of t+1 -> AwStr (other
  // buf); prefetch step t+2 -> same buf (Aw,Bkw,Bvw); counted wait at p3 tail.
  auto kstep = [&](const unsigned short* Ar, const unsigned short* Bkr,
                   const unsigned short* Bvr, unsigned short* AwStr,
                   unsigned short* Aw, unsigned short* Bkw, unsigned short* Bvw,
                   int t) {
    const bool s1 = (t + 1 < NSTEP);
    const bool s2 = (t + 2 < NSTEP);
    short8 bkf[2][2], bvf[2][2];
#pragma unroll
    for (int p = 0; p < 4; ++p) {
      short8 af[2][2];
#pragma unroll
      for (int rp = 0; rp < 2; ++rp) {
        int row = wr + (2 * p + rp) * 16 + la;
        af[rp][0] = *(const short8*)(Ar + row * BK + sl0 * 8);
        af[rp][1] = *(const short8*)(Ar + row * BK + sl1 * 8);
      }
      if (p == 0) {
#pragma unroll
        for (int j = 0; j < 2; ++j) {
          int row = wc + j * 16 + la;
          bkf[j][0] = *(const short8*)(Bkr + row * BK + sl0 * 8);
          bkf[j][1] = *(const short8*)(Bkr + row * BK + sl1 * 8);
          bvf[j][0] = *(const short8*)(Bvr + row * BK + sl0 * 8);
          bvf[j][1] = *(const short8*)(Bvr + row * BK + sl1 * 8);
        }
        if (s1) SA(AwStr, t + 1, 3);              // straggler for step t+1
      }
      if (p == 1 && s2) { SA(Aw, t + 2, 0); SB(Bkb, Bkw, t + 2, 0); }
      if (p == 2 && s2) { SA(Aw, t + 2, 1); SB(Bkb, Bkw, t + 2, 1);
                          SB(Bvb, Bvw, t + 2, 0); }
      if (p == 3 && s2) { SA(Aw, t + 2, 2); SB(Bvb, Bvw, t + 2, 1); }
      __builtin_amdgcn_s_barrier();
      __builtin_amdgcn_s_setprio(1);
#pragma unroll
      for (int rp = 0; rp < 2; ++rp)
#pragma unroll
        for (int j = 0; j < 2; ++j)
#pragma unroll
          for (int kk = 0; kk < 2; ++kk) {
            ak[2*p+rp][j] = __builtin_amdgcn_mfma_f32_16x16x32_bf16(
                af[rp][kk], bkf[j][kk], ak[2*p+rp][j], 0, 0, 0);
            av[2*p+rp][j] = __builtin_amdgcn_mfma_f32_16x16x32_bf16(
                af[rp][kk], bvf[j][kk], av[2*p+rp][j], 0, 0, 0);
          }
      __builtin_amdgcn_s_setprio(0);
      if (p == 3 && s1) {                          // wait for step t+1's loads
        if (t + 1 == NSTEP - 1) VMCNT0(); else VMCNT7();
      }
      __builtin_amdgcn_s_barrier();
    }
  };

  // prologue: step 0 fully (8), step 1 partially (7, A-q3 comes as straggler)
#pragma unroll
  for (int p = 0; p < 4; ++p) SA(As0, 0, p);
  SB(Bkb, Bk0, 0, 0); SB(Bkb, Bk0, 0, 1);
  SB(Bvb, Bv0, 0, 0); SB(Bvb, Bv0, 0, 1);
#pragma unroll
  for (int p = 0; p < 3; ++p) SA(As1, 1, p);
  SB(Bkb, Bk1, 1, 0); SB(Bkb, Bk1, 1, 1);
  SB(Bvb, Bv1, 1, 0); SB(Bvb, Bv1, 1, 1);
  VMCNT7();
  __builtin_amdgcn_s_barrier();

  for (int t = 0; t < NSTEP; t += 2) {
    kstep(As0, Bk0, Bv0, As1, As0, Bk0, Bv0, t);
    kstep(As1, Bk1, Bv1, As0, As1, Bk1, Bv1, t + 1);
  }

  // ---- fused column reduction ----
  const int b = bm >> 4;               // 16 bm-blocks per batch (256 rows each)
  float kp[2] = {0.f, 0.f};
  float vp[2] = {0.f, 0.f};
#pragma unroll
  for (int j = 0; j < 2; j++)
#pragma unroll
    for (int mi = 0; mi < 8; mi++)
#pragma unroll
      for (int r = 0; r < 4; r++) {
        float kk = phi_f(ak[mi][j][r]);
        kp[j] += kk;
        vp[j] += kk * av[mi][j][r];
      }
#pragma unroll
  for (int j = 0; j < 2; j++) {
    kp[j] += __shfl_xor(kp[j], 16, 64); kp[j] += __shfl_xor(kp[j], 32, 64);
    vp[j] += __shfl_xor(vp[j], 16, 64); vp[j] += __shfl_xor(vp[j], 32, 64);
  }
  if (lane < 16) {
#pragma unroll
    for (int j = 0; j < 2; j++) {
      int col = bn * BN + wc + j * 16 + lane;
      atomicAdd(ksum  + (size_t)b * D_MODEL + col, kp[j]);
      atomicAdd(kvsum + (size_t)b * D_MODEL + col, vp[j]);
    }
  }
}

// ---------------- phase 2: q/g GEMM with fused finalize ---------------------
// Waves 0-3 compute q on 256x128 (128x64 each), waves 4-7 compute g. A wave's
// 64 cols = exactly one head -> s,z reduce fully in-wave.
__global__ __launch_bounds__(512, 1) void gemm_qg_kernel(
    const unsigned short* __restrict__ A,
    const unsigned short* __restrict__ Wq, const unsigned short* __restrict__ Wg,
    const float* __restrict__ x, const float* __restrict__ bg,
    const float* __restrict__ ksum, const float* __restrict__ kvsum,
    float* __restrict__ out)
{
  __shared__ __align__(16) unsigned short As0[BM * BK], As1[BM * BK];
  __shared__ __align__(16) unsigned short Bq0[BN * BK], Bq1[BN * BK];
  __shared__ __align__(16) unsigned short Bg0[BN * BK], Bg1[BN * BK];
  __shared__ float o_lds[2 * BM];      // [head_local][row_local]

  const int bid = blockIdx.x;
  const int sw  = (bid & 7) * 64 + (bid >> 3);
  const int bn  = sw & 7;
  const int bm  = sw >> 3;

  const int tid  = threadIdx.x;
  const int lane = tid & 63;
  const int w    = tid >> 6;           // 0..7
  const int is_g = w >> 2;
  const int wl   = w & 3;
  const int wr   = (wl >> 1) * 128;
  const int wc   = (wl & 1) * 64;
  const int la   = lane & 15;
  const int l4   = lane >> 4;

  floatx4 acc[8][4];
#pragma unroll
  for (int i = 0; i < 8; i++)
#pragma unroll
    for (int j = 0; j < 4; j++) { floatx4 zz = {0.f,0.f,0.f,0.f}; acc[i][j] = zz; }

  const unsigned short* Ablk = A  + (size_t)bm * BM * KDIM;
  const unsigned short* Bqb  = Wq + (size_t)bn * BN * KDIM;
  const unsigned short* Bgb  = Wg + (size_t)bn * BN * KDIM;

  const int lr  = tid >> 3;
  const int slt = tid & 7;
  const int arb = (lr & 31) + ((lr >> 5) << 7);
  const int aG  = arb * KDIM + ((slt ^ (lr & 7)) << 3);
  const int aL  = arb * BK + slt * 8;
  int boff[2], bL[2];
#pragma unroll
  for (int i = 0; i < 2; i++) {
    int s = tid + i * 512; int r = s >> 3;
    boff[i] = r * KDIM + (((s & 7) ^ (r & 7)) << 3);
    bL[i]   = s * 8;
  }

  auto SA = [&](unsigned short* dst, int s, int p) {
    GLD16(Ablk + aG + (32 * p) * KDIM + s * BK, dst + aL + p * (32 * BK));
  };
  auto SB = [&](const unsigned short* g, unsigned short* dst, int s, int i) {
    GLD16(g + boff[i] + s * BK, dst + bL[i]);
  };

  const int sl0 = (0 * 4 + l4) ^ (la & 7);
  const int sl1 = (1 * 4 + l4) ^ (la & 7);

  auto kstep = [&](const unsigned short* Ar, const unsigned short* Bqr,
                   const unsigned short* Bgr, unsigned short* AwStr,
                   unsigned short* Aw, unsigned short* Bqw, unsigned short* Bgw,
                   int t) {
    const bool s1 = (t + 1 < NSTEP);
    const bool s2 = (t + 2 < NSTEP);
    const unsigned short* Br = is_g ? Bgr : Bqr;
    short8 bf[4][2];
#pragma unroll
    for (int p = 0; p < 4; ++p) {
      short8 af[2][2];
#pragma unroll
      for (int rp = 0; rp < 2; ++rp) {
        int row = wr + (2 * p + rp) * 16 + la;
        af[rp][0] = *(const short8*)(Ar + row * BK + sl0 * 8);
        af[rp][1] = *(const short8*)(Ar + row * BK + sl1 * 8);
      }
      if (p == 0) {
#pragma unroll
        for (int j = 0; j < 4; ++j) {
          int row = wc + j * 16 + la;
          bf[j][0] = *(const short8*)(Br + row * BK + sl0 * 8);
          bf[j][1] = *(const short8*)(Br + row * BK + sl1 * 8);
        }
        if (s1) SA(AwStr, t + 1, 3);
      }
      if (p == 1 && s2) { SA(Aw, t + 2, 0); SB(Bqb, Bqw, t + 2, 0); }
      if (p == 2 && s2) { SA(Aw, t + 2, 1); SB(Bqb, Bqw, t + 2, 1);
                          SB(Bgb, Bgw, t + 2, 0); }
      if (p == 3 && s2) { SA(Aw, t + 2, 2); SB(Bgb, Bgw, t + 2, 1); }
      __builtin_amdgcn_s_barrier();
      __builtin_amdgcn_s_setprio(1);
#pragma unroll
      for (int rp = 0; rp < 2; ++rp)
#pragma unroll
        for (int j = 0; j < 4; ++j)
#pragma unroll
          for (int kk = 0; kk < 2; ++kk)
            acc[2*p+rp][j] = __builtin_amdgcn_mfma_f32_16x16x32_bf16(
                af[rp][kk], bf[j][kk], acc[2*p+rp][j], 0, 0, 0);
      __builtin_amdgcn_s_setprio(0);
      if (p == 3 && s1) {
        if (t + 1 == NSTEP - 1) VMCNT0(); else VMCNT7();
      }
      __builtin_amdgcn_s_barrier();
    }
  };

#pragma unroll
  for (int p = 0; p < 4; ++p) SA(As0, 0, p);
  SB(Bqb, Bq0, 0, 0); SB(Bqb, Bq0, 0, 1);
  SB(Bgb, Bg0, 0, 0); SB(Bgb, Bg0, 0, 1);
#pragma unroll
  for (int p = 0; p < 3; ++p) SA(As1, 1, p);
  SB(Bqb, Bq1, 1, 0); SB(Bqb, Bq1, 1, 1);
  SB(Bgb, Bg1, 1, 0); SB(Bgb, Bg1, 1, 1);
  VMCNT7();
  __builtin_amdgcn_s_barrier();

  for (int t = 0; t < NSTEP; t += 2) {
    kstep(As0, Bq0, Bg0, As1, As0, Bq0, Bg0, t);
    kstep(As1, Bq1, Bg1, As0, As1, Bq1, Bg1, t + 1);
  }

  // ---- fused finalize ----
  const int b  = bm >> 4;
  const int ro = l4 * 4;
  const int co = la;
  const int hl = wc >> 6;              // head_local (0/1): wave spans one head

  if (!is_g) {
    float kvv[4], ksv[4];
#pragma unroll
    for (int j = 0; j < 4; j++) {
      int col = bn * BN + wc + j * 16 + co;
      kvv[j] = kvsum[(size_t)b * D_MODEL + col];
      ksv[j] = ksum [(size_t)b * D_MODEL + col];
    }
#pragma unroll
    for (int mi = 0; mi < 8; mi++)
#pragma unroll
      for (int r = 0; r < 4; r++) {
        float s = 0.f, z = 0.f;
#pragma unroll
        for (int j = 0; j < 4; j++) {
          float qq = phi_f(acc[mi][j][r]);
          s += qq * kvv[j]; z += qq * ksv[j];
        }
#pragma unroll
        for (int m = 1; m < 16; m <<= 1) {
          s += __shfl_xor(s, m, 64);
          z += __shfl_xor(z, m, 64);
        }
        if (co == 0) o_lds[hl * BM + wr + mi * 16 + ro + r] = s / (z + EPSV);
      }
  }
  __syncthreads();
  if (is_g) {
    float bgv[4];
#pragma unroll
    for (int j = 0; j < 4; j++) bgv[j] = bg[bn * BN + wc + j * 16 + co];
#pragma unroll
    for (int mi = 0; mi < 8; mi++)
#pragma unroll
      for (int r = 0; r < 4; r++) {
        int rowl = wr + mi * 16 + ro + r;
        int grow = bm * BM + rowl;
        float ov = o_lds[hl * BM + rowl];
#pragma unroll
        for (int j = 0; j < 4; j++) {
          int gcol = bn * BN + wc + j * 16 + co;
          float gt = 1.f / (1.f + __expf(-(acc[mi][j][r] + bgv[j])));
          float xv = x[(size_t)grow * D_MODEL + gcol];
          out[(size_t)grow * D_MODEL + gcol] = gt * ov + (1.f - gt) * xv;
        }
      }
  }
}

extern "C" void kernel_launch(void* const* d_in, const int* in_sizes, int n_in,
                              void* d_out, int out_size, void* d_ws, size_t ws_size,
                              hipStream_t stream) {
  (void)in_sizes; (void)n_in; (void)out_size; (void)ws_size;
  const float* x  = (const float*)d_in[0];
  const float* Wq = (const float*)d_in[1];
  const float* Wk = (const float*)d_in[2];
  const float* Wv = (const float*)d_in[3];
  /* d_in[4] = Wo — unused by the reference */
  const float* Wg = (const float*)d_in[5];
  const float* bg = (const float*)d_in[6];
  float* out = (float*)d_out;

  char* ws = (char*)d_ws;
  const size_t xel = (size_t)MROWS * D_MODEL;
  const size_t wel = (size_t)NDIM * KDIM;
  unsigned short* xbf = (unsigned short*)ws; ws += xel * 2;
  unsigned short* wqb = (unsigned short*)ws; ws += wel * 2;
  unsigned short* wkb = (unsigned short*)ws; ws += wel * 2;
  unsigned short* wvb = (unsigned short*)ws; ws += wel * 2;
  unsigned short* wgb = (unsigned short*)ws; ws += wel * 2;
  float* ksum  = (float*)ws; ws += (size_t)BATCH * D_MODEL * 4;  // contiguous
  float* kvsum = (float*)ws; ws += (size_t)BATCH * D_MODEL * 4;

  // 1) fused converts + zero
  const long total4 = (long)NX4 + 4L * NW4 + NZ4;
  prep_kernel<<<(int)((total4 + 255) / 256), 256, 0, stream>>>(
      x, Wq, Wk, Wv, Wg, xbf, wqb, wkb, wvb, wgb, ksum);

  // 2) phase 1: k/v with fused reduction (512 blocks = 8 bn x 64 bm)
  gemm_kv_kernel<<<512, 512, 0, stream>>>(xbf, wkb, wvb, ksum, kvsum);

  // 3) phase 2: q/g with fused finalize
  gemm_qg_kernel<<<512, 512, 0, stream>>>(xbf, wqb, wgb, x, bg, ksum, kvsum, out);
}

// Round 5
// 284.799 us; speedup vs baseline: 1.0486x; 1.0048x over previous
//
#include <hip/hip_runtime.h>

#define D_MODEL 1024
#define TSEQ    4096
#define BATCH   4
#define MROWS   (BATCH * TSEQ)   // 16384
#define KDIM    1024
#define NDIM    1024
#define EPSV    1e-6f

typedef __attribute__((ext_vector_type(8))) short short8;
typedef __attribute__((ext_vector_type(4))) float floatx4;

__device__ inline unsigned short f2bf(float f) {
  unsigned u = __float_as_uint(f);
  unsigned r = (u + 0x7FFFu + ((u >> 16) & 1u)) >> 16;  // RNE
  return (unsigned short)r;
}
__device__ inline float phi_f(float x) { return x > 0.f ? x + 1.f : __expf(x); }

// async global->LDS, 16B per lane (linear dest = wave base + lane*16)
#define GLD16(gp, lp) __builtin_amdgcn_global_load_lds( \
    (const __attribute__((address_space(1))) void*)(gp), \
    (__attribute__((address_space(3))) void*)(lp), 16, 0, 0)

#define VMCNT8() asm volatile("s_waitcnt vmcnt(8)" ::: "memory")
#define VMCNT0() asm volatile("s_waitcnt vmcnt(0)" ::: "memory")

// ---------------- fused prep: fp32->bf16 (x + 4 weights) + zero ksum/kvsum ----
#define NX4 4194304   // x float4 count
#define NW4 262144    // one weight float4 count
#define NZ4 2048      // ksum+kvsum float4 count

__global__ __launch_bounds__(256) void prep_kernel(
    const float* __restrict__ x,  const float* __restrict__ wq,
    const float* __restrict__ wk, const float* __restrict__ wv,
    const float* __restrict__ wg,
    unsigned short* __restrict__ xb,  unsigned short* __restrict__ wqb,
    unsigned short* __restrict__ wkb, unsigned short* __restrict__ wvb,
    unsigned short* __restrict__ wgb, float* __restrict__ zbase)
{
  long i = (long)blockIdx.x * 256 + threadIdx.x;
  const float* src; unsigned short* dst; long j = i;
  if (j < NX4) { src = x; dst = xb; }
  else {
    j -= NX4;
    if (j < NW4) { src = wq; dst = wqb; }
    else { j -= NW4;
      if (j < NW4) { src = wk; dst = wkb; }
      else { j -= NW4;
        if (j < NW4) { src = wv; dst = wvb; }
        else { j -= NW4;
          if (j < NW4) { src = wg; dst = wgb; }
          else { j -= NW4;
            if (j < NZ4) { float4 zz = {0.f,0.f,0.f,0.f}; ((float4*)zbase)[j] = zz; }
            return;
          }
        }
      }
    }
  }
  float4 f = ((const float4*)src)[j];
  ushort4 o;
  o.x = f2bf(f.x); o.y = f2bf(f.y); o.z = f2bf(f.z); o.w = f2bf(f.w);
  ((ushort4*)dst)[j] = o;
}

// ---------------- GEMM geometry --------------------------------------------
// 256(M) x 128(N) tile, BK=64, 512 threads (8 waves), 16 K-steps.
// 2 barriers per K-step (was 8):
//   { read ALL frags of buf c (rolling A-chunks) -> 64 MFMA }   (no barriers)
//   barrier#1   // all waves' reads of buf c complete
//   stage(t+2) -> buf c ; vmcnt(8)  // drains t+1's loads; t+2's stay in flight
//   barrier#2   // buf 1-c certified complete for all waves
// vmcnt(0) only at the tail. LDS XOR swizzle slot^=row&7 (conflicts==0,
// verified r2) via inverse-swizzled GLOBAL source + swizzled ds_read.
#define BM 256
#define BN 128
#define BK 64
#define NSTEP (KDIM / BK)   // 16

// ---------------- phase 1: k/v GEMM with in-register fused reduction --------
__global__ __launch_bounds__(512, 1) void gemm_kv_kernel(
    const unsigned short* __restrict__ A,
    const unsigned short* __restrict__ Wk, const unsigned short* __restrict__ Wv,
    float* __restrict__ ksum, float* __restrict__ kvsum)
{
  __shared__ __align__(16) unsigned short As0[BM * BK], As1[BM * BK];   // 64 KB
  __shared__ __align__(16) unsigned short Bk0[BN * BK], Bk1[BN * BK];   // 32 KB
  __shared__ __align__(16) unsigned short Bv0[BN * BK], Bv1[BN * BK];   // 32 KB

  // T1 bijective XCD swizzle: 512 blocks = 8 xcd * 64
  const int bid = blockIdx.x;
  const int sw  = (bid & 7) * 64 + (bid >> 3);
  const int bn  = sw & 7;    // 0..7
  const int bm  = sw >> 3;   // 0..63

  const int tid  = threadIdx.x;
  const int lane = tid & 63;
  const int w    = tid >> 6;           // 0..7
  const int wr   = (w >> 2) * 128;     // 2 row groups
  const int wc   = (w & 3) * 32;       // 4 col groups
  const int la   = lane & 15;
  const int l4   = lane >> 4;

  floatx4 ak[8][2], av[8][2];
#pragma unroll
  for (int i = 0; i < 8; i++)
#pragma unroll
    for (int j = 0; j < 2; j++) {
      floatx4 zz = {0.f,0.f,0.f,0.f}; ak[i][j] = zz; av[i][j] = zz;
    }

  const unsigned short* Ablk = A  + (size_t)bm * BM * KDIM;
  const unsigned short* Bkb  = Wk + (size_t)bn * BN * KDIM;
  const unsigned short* Bvb  = Wv + (size_t)bn * BN * KDIM;

  // staging: A = 2048 slots (4/thread), B = 1024 slots (2/thread) per matrix
  int aoff[4], boff[2];
#pragma unroll
  for (int i = 0; i < 4; i++) {
    int s = tid + i * 512; int r = s >> 3;
    aoff[i] = r * KDIM + (((s & 7) ^ (r & 7)) << 3);
  }
#pragma unroll
  for (int i = 0; i < 2; i++) {
    int s = tid + i * 512; int r = s >> 3;
    boff[i] = r * KDIM + (((s & 7) ^ (r & 7)) << 3);
  }

  auto stage8 = [&](unsigned short* Aw, unsigned short* Bkw, unsigned short* Bvw,
                    int kt) {
#pragma unroll
    for (int i = 0; i < 4; ++i)
      GLD16(Ablk + aoff[i] + kt, Aw + (size_t)(tid + i * 512) * 8);
#pragma unroll
    for (int i = 0; i < 2; ++i) {
      GLD16(Bkb + boff[i] + kt, Bkw + (size_t)(tid + i * 512) * 8);
      GLD16(Bvb + boff[i] + kt, Bvw + (size_t)(tid + i * 512) * 8);
    }
  };

  // ds_read bases (elements): row*BK + swizzled-slot*8, immediates for the rest
  const int sl0 = (0 * 4 + l4) ^ (la & 7);
  const int sl1 = (1 * 4 + l4) ^ (la & 7);
  const int aB0 = (wr + la) * BK + sl0 * 8;
  const int aB1 = (wr + la) * BK + sl1 * 8;
  const int bB0 = (wc + la) * BK + sl0 * 8;
  const int bB1 = (wc + la) * BK + sl1 * 8;

#define KV_READ_A(dst, p) do { \
  _Pragma("unroll") for (int rp_ = 0; rp_ < 2; ++rp_) { \
    dst[rp_][0] = *(const short8*)(Ar + aB0 + (2*(p)+rp_) * (16*BK)); \
    dst[rp_][1] = *(const short8*)(Ar + aB1 + (2*(p)+rp_) * (16*BK)); } } while(0)

#define KV_MFMA(src, p) do { \
  __builtin_amdgcn_s_setprio(1); \
  _Pragma("unroll") for (int rp_ = 0; rp_ < 2; ++rp_) \
  _Pragma("unroll") for (int j_ = 0; j_ < 2; ++j_) \
  _Pragma("unroll") for (int kk_ = 0; kk_ < 2; ++kk_) { \
    ak[2*(p)+rp_][j_] = __builtin_amdgcn_mfma_f32_16x16x32_bf16( \
        src[rp_][kk_], bkf[j_][kk_], ak[2*(p)+rp_][j_], 0, 0, 0); \
    av[2*(p)+rp_][j_] = __builtin_amdgcn_mfma_f32_16x16x32_bf16( \
        src[rp_][kk_], bvf[j_][kk_], av[2*(p)+rp_][j_], 0, 0, 0); } \
  __builtin_amdgcn_s_setprio(0); } while(0)

  auto kstep = [&](const unsigned short* Ar, const unsigned short* Bkr,
                   const unsigned short* Bvr, unsigned short* Aw,
                   unsigned short* Bkw, unsigned short* Bvw, int t) {
    short8 bkf[2][2], bvf[2][2];
#pragma unroll
    for (int j = 0; j < 2; ++j) {
      bkf[j][0] = *(const short8*)(Bkr + bB0 + j * (16*BK));
      bkf[j][1] = *(const short8*)(Bkr + bB1 + j * (16*BK));
      bvf[j][0] = *(const short8*)(Bvr + bB0 + j * (16*BK));
      bvf[j][1] = *(const short8*)(Bvr + bB1 + j * (16*BK));
    }
    short8 afA[2][2], afB[2][2];
    KV_READ_A(afA, 0);
    KV_READ_A(afB, 1); KV_MFMA(afA, 0);
    KV_READ_A(afA, 2); KV_MFMA(afB, 1);
    KV_READ_A(afB, 3); KV_MFMA(afA, 2);
    KV_MFMA(afB, 3);
    __builtin_amdgcn_s_barrier();          // all reads of this buffer done
    if (t + 2 < NSTEP) { stage8(Aw, Bkw, Bvw, (t + 2) * BK); VMCNT8(); }
    else if (t + 1 < NSTEP) { VMCNT0(); }
    __builtin_amdgcn_s_barrier();          // next buffer certified ready
  };

  // prologue: steps 0,1 in flight; counted wait on step 0
  stage8(As0, Bk0, Bv0, 0);
  stage8(As1, Bk1, Bv1, BK);
  VMCNT8();
  __builtin_amdgcn_s_barrier();

  for (int t = 0; t < NSTEP; t += 2) {
    kstep(As0, Bk0, Bv0, As0, Bk0, Bv0, t);
    kstep(As1, Bk1, Bv1, As1, Bk1, Bv1, t + 1);
  }

  // ---- fused column reduction ----
  const int b = bm >> 4;               // 16 bm-blocks per batch (256 rows each)
  float kp[2] = {0.f, 0.f};
  float vp[2] = {0.f, 0.f};
#pragma unroll
  for (int j = 0; j < 2; j++)
#pragma unroll
    for (int mi = 0; mi < 8; mi++)
#pragma unroll
      for (int r = 0; r < 4; r++) {
        float kk = phi_f(ak[mi][j][r]);
        kp[j] += kk;
        vp[j] += kk * av[mi][j][r];
      }
#pragma unroll
  for (int j = 0; j < 2; j++) {
    kp[j] += __shfl_xor(kp[j], 16, 64); kp[j] += __shfl_xor(kp[j], 32, 64);
    vp[j] += __shfl_xor(vp[j], 16, 64); vp[j] += __shfl_xor(vp[j], 32, 64);
  }
  if (lane < 16) {
#pragma unroll
    for (int j = 0; j < 2; j++) {
      int col = bn * BN + wc + j * 16 + lane;
      atomicAdd(ksum  + (size_t)b * D_MODEL + col, kp[j]);
      atomicAdd(kvsum + (size_t)b * D_MODEL + col, vp[j]);
    }
  }
#undef KV_READ_A
#undef KV_MFMA
}

// ---------------- phase 2: q/g GEMM with fused finalize ---------------------
// Waves 0-3 compute q on 256x128 (128x64 each), waves 4-7 compute g. A wave's
// 64 cols = exactly one head -> s,z reduce fully in-wave.
__global__ __launch_bounds__(512, 1) void gemm_qg_kernel(
    const unsigned short* __restrict__ A,
    const unsigned short* __restrict__ Wq, const unsigned short* __restrict__ Wg,
    const float* __restrict__ x, const float* __restrict__ bg,
    const float* __restrict__ ksum, const float* __restrict__ kvsum,
    float* __restrict__ out)
{
  __shared__ __align__(16) unsigned short As0[BM * BK], As1[BM * BK];
  __shared__ __align__(16) unsigned short Bq0[BN * BK], Bq1[BN * BK];
  __shared__ __align__(16) unsigned short Bg0[BN * BK], Bg1[BN * BK];
  __shared__ float o_lds[2 * BM];      // [head_local][row_local]

  const int bid = blockIdx.x;
  const int sw  = (bid & 7) * 64 + (bid >> 3);
  const int bn  = sw & 7;
  const int bm  = sw >> 3;

  const int tid  = threadIdx.x;
  const int lane = tid & 63;
  const int w    = tid >> 6;           // 0..7
  const int is_g = w >> 2;
  const int wl   = w & 3;
  const int wr   = (wl >> 1) * 128;
  const int wc   = (wl & 1) * 64;
  const int la   = lane & 15;
  const int l4   = lane >> 4;

  floatx4 acc[8][4];
#pragma unroll
  for (int i = 0; i < 8; i++)
#pragma unroll
    for (int j = 0; j < 4; j++) { floatx4 zz = {0.f,0.f,0.f,0.f}; acc[i][j] = zz; }

  const unsigned short* Ablk = A  + (size_t)bm * BM * KDIM;
  const unsigned short* Bqb  = Wq + (size_t)bn * BN * KDIM;
  const unsigned short* Bgb  = Wg + (size_t)bn * BN * KDIM;

  int aoff[4], boff[2];
#pragma unroll
  for (int i = 0; i < 4; i++) {
    int s = tid + i * 512; int r = s >> 3;
    aoff[i] = r * KDIM + (((s & 7) ^ (r & 7)) << 3);
  }
#pragma unroll
  for (int i = 0; i < 2; i++) {
    int s = tid + i * 512; int r = s >> 3;
    boff[i] = r * KDIM + (((s & 7) ^ (r & 7)) << 3);
  }

  auto stage8 = [&](unsigned short* Aw, unsigned short* Bqw, unsigned short* Bgw,
                    int kt) {
#pragma unroll
    for (int i = 0; i < 4; ++i)
      GLD16(Ablk + aoff[i] + kt, Aw + (size_t)(tid + i * 512) * 8);
#pragma unroll
    for (int i = 0; i < 2; ++i) {
      GLD16(Bqb + boff[i] + kt, Bqw + (size_t)(tid + i * 512) * 8);
      GLD16(Bgb + boff[i] + kt, Bgw + (size_t)(tid + i * 512) * 8);
    }
  };

  const int sl0 = (0 * 4 + l4) ^ (la & 7);
  const int sl1 = (1 * 4 + l4) ^ (la & 7);
  const int aB0 = (wr + la) * BK + sl0 * 8;
  const int aB1 = (wr + la) * BK + sl1 * 8;
  const int bB0 = (wc + la) * BK + sl0 * 8;
  const int bB1 = (wc + la) * BK + sl1 * 8;

#define QG_READ_A(dst, p) do { \
  _Pragma("unroll") for (int rp_ = 0; rp_ < 2; ++rp_) { \
    dst[rp_][0] = *(const short8*)(Ar + aB0 + (2*(p)+rp_) * (16*BK)); \
    dst[rp_][1] = *(const short8*)(Ar + aB1 + (2*(p)+rp_) * (16*BK)); } } while(0)

#define QG_MFMA(src, p) do { \
  __builtin_amdgcn_s_setprio(1); \
  _Pragma("unroll") for (int rp_ = 0; rp_ < 2; ++rp_) \
  _Pragma("unroll") for (int j_ = 0; j_ < 4; ++j_) \
  _Pragma("unroll") for (int kk_ = 0; kk_ < 2; ++kk_) { \
    acc[2*(p)+rp_][j_] = __builtin_amdgcn_mfma_f32_16x16x32_bf16( \
        src[rp_][kk_], bf[j_][kk_], acc[2*(p)+rp_][j_], 0, 0, 0); } \
  __builtin_amdgcn_s_setprio(0); } while(0)

  auto kstep = [&](const unsigned short* Ar, const unsigned short* Br,
                   unsigned short* Aw, unsigned short* Bqw, unsigned short* Bgw,
                   int t) {
    short8 bf[4][2];
#pragma unroll
    for (int j = 0; j < 4; ++j) {
      bf[j][0] = *(const short8*)(Br + bB0 + j * (16*BK));
      bf[j][1] = *(const short8*)(Br + bB1 + j * (16*BK));
    }
    short8 afA[2][2], afB[2][2];
    QG_READ_A(afA, 0);
    QG_READ_A(afB, 1); QG_MFMA(afA, 0);
    QG_READ_A(afA, 2); QG_MFMA(afB, 1);
    QG_READ_A(afB, 3); QG_MFMA(afA, 2);
    QG_MFMA(afB, 3);
    __builtin_amdgcn_s_barrier();
    if (t + 2 < NSTEP) { stage8(Aw, Bqw, Bgw, (t + 2) * BK); VMCNT8(); }
    else if (t + 1 < NSTEP) { VMCNT0(); }
    __builtin_amdgcn_s_barrier();
  };

  stage8(As0, Bq0, Bg0, 0);
  stage8(As1, Bq1, Bg1, BK);
  VMCNT8();
  __builtin_amdgcn_s_barrier();

  for (int t = 0; t < NSTEP; t += 2) {
    kstep(As0, is_g ? Bg0 : Bq0, As0, Bq0, Bg0, t);
    kstep(As1, is_g ? Bg1 : Bq1, As1, Bq1, Bg1, t + 1);
  }

  // ---- fused finalize ----
  const int b  = bm >> 4;
  const int ro = l4 * 4;
  const int co = la;
  const int hl = wc >> 6;              // head_local (0/1): wave spans one head

  if (!is_g) {
    float kvv[4], ksv[4];
#pragma unroll
    for (int j = 0; j < 4; j++) {
      int col = bn * BN + wc + j * 16 + co;
      kvv[j] = kvsum[(size_t)b * D_MODEL + col];
      ksv[j] = ksum [(size_t)b * D_MODEL + col];
    }
#pragma unroll
    for (int mi = 0; mi < 8; mi++)
#pragma unroll
      for (int r = 0; r < 4; r++) {
        float s = 0.f, z = 0.f;
#pragma unroll
        for (int j = 0; j < 4; j++) {
          float qq = phi_f(acc[mi][j][r]);
          s += qq * kvv[j]; z += qq * ksv[j];
        }
#pragma unroll
        for (int m = 1; m < 16; m <<= 1) {
          s += __shfl_xor(s, m, 64);
          z += __shfl_xor(z, m, 64);
        }
        if (co == 0) o_lds[hl * BM + wr + mi * 16 + ro + r] = s / (z + EPSV);
      }
  }
  __syncthreads();
  if (is_g) {
    float bgv[4];
#pragma unroll
    for (int j = 0; j < 4; j++) bgv[j] = bg[bn * BN + wc + j * 16 + co];
#pragma unroll
    for (int mi = 0; mi < 8; mi++)
#pragma unroll
      for (int r = 0; r < 4; r++) {
        int rowl = wr + mi * 16 + ro + r;
        int grow = bm * BM + rowl;
        float ov = o_lds[hl * BM + rowl];
#pragma unroll
        for (int j = 0; j < 4; j++) {
          int gcol = bn * BN + wc + j * 16 + co;
          float gt = 1.f / (1.f + __expf(-(acc[mi][j][r] + bgv[j])));
          float xv = x[(size_t)grow * D_MODEL + gcol];
          out[(size_t)grow * D_MODEL + gcol] = gt * ov + (1.f - gt) * xv;
        }
      }
  }
#undef QG_READ_A
#undef QG_MFMA
}

extern "C" void kernel_launch(void* const* d_in, const int* in_sizes, int n_in,
                              void* d_out, int out_size, void* d_ws, size_t ws_size,
                              hipStream_t stream) {
  (void)in_sizes; (void)n_in; (void)out_size; (void)ws_size;
  const float* x  = (const float*)d_in[0];
  const float* Wq = (const float*)d_in[1];
  const float* Wk = (const float*)d_in[2];
  const float* Wv = (const float*)d_in[3];
  /* d_in[4] = Wo — unused by the reference */
  const float* Wg = (const float*)d_in[5];
  const float* bg = (const float*)d_in[6];
  float* out = (float*)d_out;

  char* ws = (char*)d_ws;
  const size_t xel = (size_t)MROWS * D_MODEL;
  const size_t wel = (size_t)NDIM * KDIM;
  unsigned short* xbf = (unsigned short*)ws; ws += xel * 2;
  unsigned short* wqb = (unsigned short*)ws; ws += wel * 2;
  unsigned short* wkb = (unsigned short*)ws; ws += wel * 2;
  unsigned short* wvb = (unsigned short*)ws; ws += wel * 2;
  unsigned short* wgb = (unsigned short*)ws; ws += wel * 2;
  float* ksum  = (float*)ws; ws += (size_t)BATCH * D_MODEL * 4;  // contiguous
  float* kvsum = (float*)ws; ws += (size_t)BATCH * D_MODEL * 4;

  // 1) fused converts + zero
  const long total4 = (long)NX4 + 4L * NW4 + NZ4;
  prep_kernel<<<(int)((total4 + 255) / 256), 256, 0, stream>>>(
      x, Wq, Wk, Wv, Wg, xbf, wqb, wkb, wvb, wgb, ksum);

  // 2) phase 1: k/v with fused reduction (512 blocks = 8 bn x 64 bm)
  gemm_kv_kernel<<<512, 512, 0, stream>>>(xbf, wkb, wvb, ksum, kvsum);

  // 3) phase 2: q/g with fused finalize
  gemm_qg_kernel<<<512, 512, 0, stream>>>(xbf, wqb, wgb, x, bg, ksum, kvsum, out);
}